// Round 1
// baseline (3429.575 us; speedup 1.0000x reference)
//
#include <hip/hip_runtime.h>

#define N_NODES 20000
#define N_EDGES 640000
#define TT 64
#define CIN 64
#define CSS 128
#define CTT 128
#define KK 3
#define LN_EPS 1e-5f

__device__ __forceinline__ void fma4(float4& a, float c, const float4 v) {
    a.x = fmaf(c, v.x, a.x); a.y = fmaf(c, v.y, a.y);
    a.z = fmaf(c, v.z, a.z); a.w = fmaf(c, v.w, a.w);
}

// ---- conv weight transpose: [CT][CS][K] -> [K][CS][CT] (coalesced inner ct) ----
__global__ void k_wtrans(const float* __restrict__ cw, float* __restrict__ cwt) {
    int i = blockIdx.x * blockDim.x + threadIdx.x;
    if (i >= CTT * CSS * KK) return;
    int k  = i % KK;
    int cs = (i / KK) % CSS;
    int ct = i / (KK * CSS);
    cwt[(k * CSS + cs) * CTT + ct] = cw[i];
}

__global__ void k_init(float* deg, int* cnt, int* fill) {
    int i = blockIdx.x * blockDim.x + threadIdx.x;
    if (i < N_NODES) { deg[i] = 1.0f; cnt[i] = 0; fill[i] = 0; }
}

__global__ void k_deg(const int* __restrict__ ei, const float* __restrict__ ew,
                      float* deg, int* cnt) {
    int e = blockIdx.x * blockDim.x + threadIdx.x;
    if (e >= N_EDGES) return;
    int d = ei[N_EDGES + e];
    atomicAdd(&deg[d], ew[e]);
    atomicAdd(&cnt[d], 1);
}

__global__ void k_dinv(const float* __restrict__ deg, float* __restrict__ dinv) {
    int i = blockIdx.x * blockDim.x + threadIdx.x;
    if (i < N_NODES) dinv[i] = rsqrtf(deg[i]);
}

// single-block exclusive scan of cnt -> row_ptr (N=20000, trivial)
__global__ void k_scan(const int* __restrict__ cnt, int* __restrict__ row_ptr) {
    __shared__ int sums[256];
    const int tid = threadIdx.x;
    const int CH = (N_NODES + 255) / 256;  // 79
    int b = tid * CH, e = min(b + CH, N_NODES);
    int s = 0;
    for (int i = b; i < e; ++i) s += cnt[i];
    const int own = s;
    sums[tid] = s;
    __syncthreads();
    for (int off = 1; off < 256; off <<= 1) {
        int v = 0;
        if (tid >= off) v = sums[tid - off];
        __syncthreads();
        if (tid >= off) sums[tid] += v;
        __syncthreads();
    }
    int run = sums[tid] - own;  // exclusive base for this thread's chunk
    for (int i = b; i < e; ++i) { row_ptr[i] = run; run += cnt[i]; }
    if (tid == 255) row_ptr[N_NODES] = sums[255];
}

__global__ void k_scatter(const int* __restrict__ ei, const float* __restrict__ ew,
                          const float* __restrict__ dinv, const int* __restrict__ row_ptr,
                          int* fill, int* __restrict__ ssrc, float* __restrict__ scoef) {
    int e = blockIdx.x * blockDim.x + threadIdx.x;
    if (e >= N_EDGES) return;
    int s = ei[e], d = ei[N_EDGES + e];
    int p = row_ptr[d] + atomicAdd(&fill[d], 1);
    ssrc[p] = s;
    scoef[p] = dinv[s] * ew[e] * dinv[d];
}

// ---- one block per node: aggregate -> GCN matmul+ReLU -> conv -> LN+residual ----
__global__ __launch_bounds__(256, 2)
void k_fused(const float* __restrict__ x, const float* __restrict__ Wg,
             const float* __restrict__ bg, const float* __restrict__ cwt,
             const float* __restrict__ cb, const float* __restrict__ lng,
             const float* __restrict__ lnb, const float* __restrict__ rw,
             const float* __restrict__ rb, const float* __restrict__ dinv,
             const int* __restrict__ row_ptr, const int* __restrict__ ssrc,
             const float* __restrict__ scoef, float* __restrict__ out)
{
    __shared__ __align__(16) float sh_x[TT * CIN];         // 16 KB: xagg, later x[n]
    __shared__ __align__(16) float sh_s[(TT + 2) * CSS];   // 33 KB: relu(gcn), zero-padded rows 0,65

    const int n   = blockIdx.x;
    const int tid = threadIdx.x;
    const int cg  = tid & 31;   // channel-quad index: covers 128 ch as 32 float4
    const int tg  = tid >> 5;   // time group: rows tg*8 .. tg*8+7

    // zero the conv halo rows
    if (tid < CSS) sh_s[tid] = 0.0f;
    else           sh_s[(TT + 1) * CSS + (tid - CSS)] = 0.0f;

    // ---- Phase 1: xagg[n] = dinv^2 * x[n] + sum_e coef_e * x[src_e]  (reg accumulate)
    const float4* xn4 = (const float4*)(x + (size_t)n * (TT * CIN));
    const float di = dinv[n];
    const float sc = di * di;
    float4 a0 = xn4[tid], a1 = xn4[tid + 256], a2 = xn4[tid + 512], a3 = xn4[tid + 768];
    a0.x *= sc; a0.y *= sc; a0.z *= sc; a0.w *= sc;
    a1.x *= sc; a1.y *= sc; a1.z *= sc; a1.w *= sc;
    a2.x *= sc; a2.y *= sc; a2.z *= sc; a2.w *= sc;
    a3.x *= sc; a3.y *= sc; a3.z *= sc; a3.w *= sc;

    const int e0 = row_ptr[n], e1 = row_ptr[n + 1];
    int   sN = 0; float cN = 0.0f;
    if (e0 < e1) { sN = ssrc[e0]; cN = scoef[e0]; }
    for (int p = e0; p < e1; ++p) {
        const int   s = sN;
        const float c = cN;
        if (p + 1 < e1) { sN = ssrc[p + 1]; cN = scoef[p + 1]; }
        const float4* xs4 = (const float4*)(x + (size_t)s * (TT * CIN));
        float4 v0 = xs4[tid], v1 = xs4[tid + 256], v2 = xs4[tid + 512], v3 = xs4[tid + 768];
        fma4(a0, c, v0); fma4(a1, c, v1); fma4(a2, c, v2); fma4(a3, c, v3);
    }
    float4* shx4 = (float4*)sh_x;
    shx4[tid] = a0; shx4[tid + 256] = a1; shx4[tid + 512] = a2; shx4[tid + 768] = a3;
    __syncthreads();

    // ---- Phase 2: s = relu(xagg @ Wg + bg) -> sh_s rows 1..64
    float acc[8][4];
    {
        const float4 b4 = ((const float4*)bg)[cg];
        #pragma unroll
        for (int i = 0; i < 8; ++i) { acc[i][0] = b4.x; acc[i][1] = b4.y; acc[i][2] = b4.z; acc[i][3] = b4.w; }
    }
    for (int c = 0; c < CIN; ++c) {
        const float4 w = ((const float4*)(Wg + c * CSS))[cg];
        #pragma unroll
        for (int i = 0; i < 8; ++i) {
            const float xa = sh_x[(tg * 8 + i) * CIN + c];
            acc[i][0] = fmaf(xa, w.x, acc[i][0]);
            acc[i][1] = fmaf(xa, w.y, acc[i][1]);
            acc[i][2] = fmaf(xa, w.z, acc[i][2]);
            acc[i][3] = fmaf(xa, w.w, acc[i][3]);
        }
    }
    #pragma unroll
    for (int i = 0; i < 8; ++i) {
        float4 sv;
        sv.x = fmaxf(acc[i][0], 0.0f); sv.y = fmaxf(acc[i][1], 0.0f);
        sv.z = fmaxf(acc[i][2], 0.0f); sv.w = fmaxf(acc[i][3], 0.0f);
        ((float4*)(sh_s + (tg * 8 + i + 1) * CSS))[cg] = sv;
    }
    __syncthreads();

    // refill sh_x with x[n] for the residual (all sh_x readers passed the barrier)
    shx4[tid]       = xn4[tid];
    shx4[tid + 256] = xn4[tid + 256];
    shx4[tid + 512] = xn4[tid + 512];
    shx4[tid + 768] = xn4[tid + 768];

    // ---- Phase 3: temporal conv, y[t][ct] = cb + sum_{k,cs} s[t+k-1][cs]*w[ct][cs][k]
    float acy[8][4];
    {
        const float4 b4 = ((const float4*)cb)[cg];
        #pragma unroll
        for (int i = 0; i < 8; ++i) { acy[i][0] = b4.x; acy[i][1] = b4.y; acy[i][2] = b4.z; acy[i][3] = b4.w; }
    }
    for (int k = 0; k < KK; ++k) {
        for (int cs = 0; cs < CSS; ++cs) {
            const float4 w = ((const float4*)(cwt + (k * CSS + cs) * CTT))[cg];
            #pragma unroll
            for (int i = 0; i < 8; ++i) {
                const float sv = sh_s[(tg * 8 + i + k) * CSS + cs];  // row t+k (pad offset +1)
                acy[i][0] = fmaf(sv, w.x, acy[i][0]);
                acy[i][1] = fmaf(sv, w.y, acy[i][1]);
                acy[i][2] = fmaf(sv, w.z, acy[i][2]);
                acy[i][3] = fmaf(sv, w.w, acy[i][3]);
            }
        }
    }
    __syncthreads();  // orders sh_x refill vs. reads below

    // ---- Phase 4: residual matmul from sh_x (= x[n]), then LN + add + store
    float resa[8][4];
    {
        const float4 b4 = ((const float4*)rb)[cg];
        #pragma unroll
        for (int i = 0; i < 8; ++i) { resa[i][0] = b4.x; resa[i][1] = b4.y; resa[i][2] = b4.z; resa[i][3] = b4.w; }
    }
    for (int c = 0; c < CIN; ++c) {
        const float4 w = ((const float4*)(rw + c * CTT))[cg];
        #pragma unroll
        for (int i = 0; i < 8; ++i) {
            const float xv = sh_x[(tg * 8 + i) * CIN + c];
            resa[i][0] = fmaf(xv, w.x, resa[i][0]);
            resa[i][1] = fmaf(xv, w.y, resa[i][1]);
            resa[i][2] = fmaf(xv, w.z, resa[i][2]);
            resa[i][3] = fmaf(xv, w.w, resa[i][3]);
        }
    }
    const float4 g4  = ((const float4*)lng)[cg];
    const float4 lb4 = ((const float4*)lnb)[cg];
    #pragma unroll
    for (int i = 0; i < 8; ++i) {
        float sm = acy[i][0] + acy[i][1] + acy[i][2] + acy[i][3];
        float sq = acy[i][0] * acy[i][0] + acy[i][1] * acy[i][1]
                 + acy[i][2] * acy[i][2] + acy[i][3] * acy[i][3];
        #pragma unroll
        for (int m = 16; m >= 1; m >>= 1) {
            sm += __shfl_xor(sm, m, 32);
            sq += __shfl_xor(sq, m, 32);
        }
        const float mu  = sm * (1.0f / CTT);
        const float var = sq * (1.0f / CTT) - mu * mu;
        const float rs  = rsqrtf(var + LN_EPS);
        const int t = tg * 8 + i;
        float4 o;
        o.x = fmaf((acy[i][0] - mu) * rs, g4.x, lb4.x) + resa[i][0];
        o.y = fmaf((acy[i][1] - mu) * rs, g4.y, lb4.y) + resa[i][1];
        o.z = fmaf((acy[i][2] - mu) * rs, g4.z, lb4.z) + resa[i][2];
        o.w = fmaf((acy[i][3] - mu) * rs, g4.w, lb4.w) + resa[i][3];
        ((float4*)(out + ((size_t)n * TT + t) * CTT))[cg] = o;
    }
}

extern "C" void kernel_launch(void* const* d_in, const int* in_sizes, int n_in,
                              void* d_out, int out_size, void* d_ws, size_t ws_size,
                              hipStream_t stream) {
    const float* x   = (const float*)d_in[0];
    const int*   ei  = (const int*)d_in[1];
    const float* ew  = (const float*)d_in[2];
    const float* Wg  = (const float*)d_in[3];
    const float* bg  = (const float*)d_in[4];
    const float* cw  = (const float*)d_in[5];
    const float* cb  = (const float*)d_in[6];
    const float* lng = (const float*)d_in[7];
    const float* lnb = (const float*)d_in[8];
    const float* rw  = (const float*)d_in[9];
    const float* rb  = (const float*)d_in[10];
    float* out = (float*)d_out;

    char* ws = (char*)d_ws;
    size_t off = 0;
    auto alloc = [&](size_t bytes) {
        void* p = ws + off;
        off += (bytes + 255) & ~(size_t)255;
        return p;
    };
    float* deg   = (float*)alloc(N_NODES * 4);
    float* dinv  = (float*)alloc(N_NODES * 4);
    int*   cnt   = (int*)alloc(N_NODES * 4);
    int*   rowp  = (int*)alloc((N_NODES + 1) * 4);
    int*   fill  = (int*)alloc(N_NODES * 4);
    int*   ssrc  = (int*)alloc(N_EDGES * 4);
    float* scoef = (float*)alloc(N_EDGES * 4);
    float* cwt   = (float*)alloc((size_t)KK * CSS * CTT * 4);

    hipLaunchKernelGGL(k_wtrans,  dim3((CTT * CSS * KK + 255) / 256), dim3(256), 0, stream, cw, cwt);
    hipLaunchKernelGGL(k_init,    dim3((N_NODES + 255) / 256), dim3(256), 0, stream, deg, cnt, fill);
    hipLaunchKernelGGL(k_deg,     dim3((N_EDGES + 255) / 256), dim3(256), 0, stream, ei, ew, deg, cnt);
    hipLaunchKernelGGL(k_dinv,    dim3((N_NODES + 255) / 256), dim3(256), 0, stream, deg, dinv);
    hipLaunchKernelGGL(k_scan,    dim3(1), dim3(256), 0, stream, cnt, rowp);
    hipLaunchKernelGGL(k_scatter, dim3((N_EDGES + 255) / 256), dim3(256), 0, stream, ei, ew, dinv, rowp, fill, ssrc, scoef);
    hipLaunchKernelGGL(k_fused,   dim3(N_NODES), dim3(256), 0, stream,
                       x, Wg, bg, cwt, cb, lng, lnb, rw, rb, dinv, rowp, ssrc, scoef, out);
}